// Round 2
// baseline (222.858 us; speedup 1.0000x reference)
//
#include <hip/hip_runtime.h>

// BinaryAggregationLayer: batch=4096, in_width=8192, out_width=8191.
// dest[i] = min(i, 8190)  =>  out[b][j] = x[b][j] for j<8190,
//                             out[b][8190] = 0.5*(x[b][8190]+x[b][8191])
// then clip to +-10000. Pure memory-bound strided copy.
//
// Flat-index mapping: o = b*8191 + j  ->  input i = b*8192 + j = o + b.
//
// V2b: vectorized fast path. Input flat index i0 = 4t + b is only 4B-aligned,
// but gfx950 global loads only need element (dword) alignment, so we issue a
// single global_load_dwordx4 at align(4) instead of 4 scalar dword loads.
// Row-wrap / merge handling (j0 >= 8187) falls back to the scalar loop —
// ~4 of every 8191 threads. Store side uses clang ext_vector float4
// (native vector type) so __builtin_nontemporal_store accepts it.

#define OUTW   8191u
#define CLAMPV 10000.0f

// Native clang vector types (NOT HIP_vector_type) — builtin-compatible.
typedef float f4   __attribute__((ext_vector_type(4)));              // 16B aligned
typedef float f4a4 __attribute__((ext_vector_type(4), aligned(4)));  // 4B aligned

__global__ __launch_bounds__(256) void bagg_copy_kernel(
    const float* __restrict__ x, float* __restrict__ out, unsigned int total4) {
    unsigned int t = blockIdx.x * blockDim.x + threadIdx.x;
    if (t >= total4) return;

    unsigned int o0 = t * 4u;                 // first flat output index
    unsigned int b  = o0 / OUTW;              // magic-mul division by 8191
    unsigned int j  = o0 - b * OUTW;

    f4 vv;
    if (j < OUTW - 4u) {
        // Fast path: j..j+3 <= 8189 < 8190 -> no merge node, no row wrap.
        // Input elements are contiguous at x + o0 + b (4B-aligned).
        f4a4 v = *reinterpret_cast<const f4a4*>(x + (o0 + b));
        vv.x = fminf(fmaxf(v.x, -CLAMPV), CLAMPV);
        vv.y = fminf(fmaxf(v.y, -CLAMPV), CLAMPV);
        vv.z = fminf(fmaxf(v.z, -CLAMPV), CLAMPV);
        vv.w = fminf(fmaxf(v.w, -CLAMPV), CLAMPV);
    } else {
        // Slow path (j0 in {8187,8188,8189,8190}): merge node and/or row wrap.
        float r[4];
#pragma unroll
        for (int k = 0; k < 4; ++k) {
            unsigned int i = o0 + (unsigned int)k + b;
            float v = x[i];
            if (j == OUTW - 1u) {             // merged node: mean of last two inputs
                v = 0.5f * (v + x[i + 1]);
            }
            v = fminf(fmaxf(v, -CLAMPV), CLAMPV);
            r[k] = v;
            ++j;
            if (j == OUTW) { j = 0u; ++b; }   // advance into next row (i shifts by 2)
        }
        vv.x = r[0]; vv.y = r[1]; vv.z = r[2]; vv.w = r[3];
    }

    // Output side is exactly 16B-aligned at float4 index t; stream it past cache.
    __builtin_nontemporal_store(vv, reinterpret_cast<f4*>(out) + t);
}

extern "C" void kernel_launch(void* const* d_in, const int* in_sizes, int n_in,
                              void* d_out, int out_size, void* d_ws, size_t ws_size,
                              hipStream_t stream) {
    const float* x = (const float*)d_in[0];
    float* out = (float*)d_out;

    const unsigned int total  = 4096u * OUTW;             // 33,550,336
    const unsigned int total4 = total / 4u;               // 8,387,584 (exact)
    const unsigned int block  = 256;
    const unsigned int grid   = (total4 + block - 1) / block; // 32,764 (exact, no tail)

    bagg_copy_kernel<<<grid, block, 0, stream>>>(x, out, total4);
}

// Round 3
// 222.766 us; speedup vs baseline: 1.0004x; 1.0004x over previous
//
#include <hip/hip_runtime.h>

// BinaryAggregationLayer: batch=4096, in_width=8192, out_width=8191.
// dest[i] = min(i, 8190)  =>  out[b][j] = x[b][j] for j<8190,
//                             out[b][8190] = 0.5*(x[b][8190]+x[b][8191])
// then clip to +-10000. Pure memory-bound strided copy.
//
// Flat-index mapping: o = b*8191 + j  ->  input i = b*8192 + j = o + b.
//
// V3: grid-stride with 2048 blocks (8 blocks/CU x 256 CU, 32 waves/CU = full
// occupancy). V2's 32,764 one-shot workgroups paid command-processor dispatch
// + per-thread prologue (magic-div, branch, exit) once per 4 KiB moved; now
// each thread streams 16 float4 chunks, amortizing that 16x. Fast path is one
// 4B-aligned global_load_dwordx4 (gfx950 needs only element alignment) +
// med3-clamps + one aligned nontemporal dwordx4 store. Slow path (merge node /
// row wrap, j0 >= 8187) is ~4 of every 8191 float4s.

#define OUTW   8191u
#define CLAMPV 10000.0f

// Native clang vector types (NOT HIP_vector_type) — builtin-compatible.
typedef float f4   __attribute__((ext_vector_type(4)));              // 16B aligned
typedef float f4a4 __attribute__((ext_vector_type(4), aligned(4)));  // 4B aligned

__global__ __launch_bounds__(256) void bagg_copy_kernel(
    const float* __restrict__ x, float* __restrict__ out,
    unsigned int total4, unsigned int stride) {
    unsigned int t = blockIdx.x * blockDim.x + threadIdx.x;

    for (; t < total4; t += stride) {
        unsigned int o0 = t * 4u;                 // first flat output index
        unsigned int b  = o0 / OUTW;              // magic-mul division by 8191
        unsigned int j  = o0 - b * OUTW;

        f4 vv;
        if (j < OUTW - 4u) {
            // Fast path: j..j+3 <= 8189 < 8190 -> no merge node, no row wrap.
            // Input elements are contiguous at x + o0 + b (4B-aligned).
            f4a4 v = __builtin_nontemporal_load(
                reinterpret_cast<const f4a4*>(x + (o0 + b)));
            vv.x = fminf(fmaxf(v.x, -CLAMPV), CLAMPV);
            vv.y = fminf(fmaxf(v.y, -CLAMPV), CLAMPV);
            vv.z = fminf(fmaxf(v.z, -CLAMPV), CLAMPV);
            vv.w = fminf(fmaxf(v.w, -CLAMPV), CLAMPV);
        } else {
            // Slow path (j0 in {8187,8188,8189,8190}): merge and/or row wrap.
            float r[4];
#pragma unroll
            for (int k = 0; k < 4; ++k) {
                unsigned int i = o0 + (unsigned int)k + b;
                float v = x[i];
                if (j == OUTW - 1u) {             // merged node: mean of last two
                    v = 0.5f * (v + x[i + 1]);
                }
                v = fminf(fmaxf(v, -CLAMPV), CLAMPV);
                r[k] = v;
                ++j;
                if (j == OUTW) { j = 0u; ++b; }   // next row (input idx shifts by 2)
            }
            vv.x = r[0]; vv.y = r[1]; vv.z = r[2]; vv.w = r[3];
        }

        // Output side is exactly 16B-aligned at float4 index t; stream it.
        __builtin_nontemporal_store(vv, reinterpret_cast<f4*>(out) + t);
    }
}

extern "C" void kernel_launch(void* const* d_in, const int* in_sizes, int n_in,
                              void* d_out, int out_size, void* d_ws, size_t ws_size,
                              hipStream_t stream) {
    const float* x = (const float*)d_in[0];
    float* out = (float*)d_out;

    const unsigned int total  = 4096u * OUTW;             // 33,550,336
    const unsigned int total4 = total / 4u;               // 8,387,584 (exact)
    const unsigned int block  = 256;
    const unsigned int grid   = 2048;                     // 8 blocks/CU, 32 waves/CU
    const unsigned int stride = grid * block;             // 524,288 -> 16 iters/thread

    bagg_copy_kernel<<<grid, block, 0, stream>>>(x, out, total4, stride);
}